// Round 8
// baseline (468.656 us; speedup 1.0000x reference)
//
#include <hip/hip_runtime.h>
#include <math.h>

#define Bsz 512
#define TT 8
#define Dn 2048
#define DIN 512
#define Hh 4
#define Pn 512
#define DOUT 512
#define BD (Bsz*Dn)

typedef __attribute__((ext_vector_type(8))) short s16x8;
typedef __attribute__((ext_vector_type(4))) float f32x4;
typedef __attribute__((ext_vector_type(4))) unsigned short u16x4;

__device__ __forceinline__ unsigned short f2bf(float f) {
  unsigned int u = __float_as_uint(f);
  unsigned int r = (u + 0x7fffu + ((u >> 16) & 1u)) >> 16;
  return (unsigned short)r;
}
__device__ __forceinline__ float bf2f(unsigned short h) {
  return __uint_as_float(((unsigned int)h) << 16);
}
__device__ __forceinline__ void split2(float x, unsigned short& h, unsigned short& l) {
  h = f2bf(x);
  float r = x - bf2f(h);
  l = f2bf(r);
}

// async global->LDS, 16B per lane, LDS dest = wave-uniform base + lane*16
#define GLOAD16(g, l) __builtin_amdgcn_global_load_lds( \
    (const __attribute__((address_space(1))) unsigned int*)(g), \
    (__attribute__((address_space(3))) unsigned int*)(l), 16, 0, 0)

// ---------------- shared MFMA GEMM core (r7: 32x32 wave-tile) ----------------
// A (M,K) as Ah/Al bf16 row-major; B as BT h/l (N,K) row-major.
// 32x64 block tile, BK=64, 2 waves of 32x32 (128 threads). Triple-buffered
// LDS via global_load_lds w=16, counted vmcnt(12). r6's 16x32 wave-tile read
// 1.0 KB LDS per MFMA (LDS-read-bound at ~30us/tick); 32x32 reads 0.67 KB
// per MFMA (16 ds_read_b128 per 24 MFMA per K-step).
__device__ __forceinline__ void gemm_core(
    const unsigned short* __restrict__ Ah, const unsigned short* __restrict__ Al,
    const unsigned short* __restrict__ BTh, const unsigned short* __restrict__ BTl,
    int K, long arow0, long brow0,
    unsigned short* As /*[3][32][128]*/, unsigned short* Bs /*[3][64][128]*/,
    f32x4 acc[2][2])
{
  const int tid = threadIdx.x;
  const int lane = tid & 63, wave = tid >> 6;   // wave 0..1
  const int lh = lane >> 4;   // staging: row-within-4
  const int sc = lane & 15;   // staging: column slot

  // staging: wave w covers A rows [w*16,+16) (4 instrs), B rows [w*32,+32) (8)
  const unsigned short* gA[4];
  const unsigned short* gB[8];
  int ldA[4], ldB[8];
#pragma unroll
  for (int t = 0; t < 4; ++t) {
    int row = wave * 16 + t * 4 + lh;
    gA[t] = (sc < 8 ? Ah : Al) + (size_t)(arow0 + row) * K + (((sc & 7) ^ (row & 7)) << 3);
    ldA[t] = (wave * 16 + t * 4) * 128;
  }
#pragma unroll
  for (int t = 0; t < 8; ++t) {
    int row = wave * 32 + t * 4 + lh;
    gB[t] = (sc < 8 ? BTh : BTl) + (size_t)(brow0 + row) * K + (((sc & 7) ^ (row & 7)) << 3);
    ldB[t] = (wave * 32 + t * 4) * 128;
  }

  const int nk = K >> 6;   // >= 8 for all call sites

#define STAGE(buf, ks)                                   \
  {                                                      \
    const size_t kb = (size_t)(ks) * 64;                 \
    unsigned short* a0_ = As + (buf) * 4096;             \
    unsigned short* b0_ = Bs + (buf) * 8192;             \
    GLOAD16(gA[0] + kb, a0_ + ldA[0]);                   \
    GLOAD16(gA[1] + kb, a0_ + ldA[1]);                   \
    GLOAD16(gA[2] + kb, a0_ + ldA[2]);                   \
    GLOAD16(gA[3] + kb, a0_ + ldA[3]);                   \
    GLOAD16(gB[0] + kb, b0_ + ldB[0]);                   \
    GLOAD16(gB[1] + kb, b0_ + ldB[1]);                   \
    GLOAD16(gB[2] + kb, b0_ + ldB[2]);                   \
    GLOAD16(gB[3] + kb, b0_ + ldB[3]);                   \
    GLOAD16(gB[4] + kb, b0_ + ldB[4]);                   \
    GLOAD16(gB[5] + kb, b0_ + ldB[5]);                   \
    GLOAD16(gB[6] + kb, b0_ + ldB[6]);                   \
    GLOAD16(gB[7] + kb, b0_ + ldB[7]);                   \
  }

  // fragment LDS offsets (shorts): wave w owns rows 0..32 x cols w*32..+32
  const int wn = wave * 32;
  const int lm = lane & 15, kg4 = lane >> 4;
  int aoff[2][2][2], boff[2][2][2];
#pragma unroll
  for (int u = 0; u < 2; ++u) {
    int kg = u * 4 + kg4;
#pragma unroll
    for (int mt = 0; mt < 2; ++mt) {
      int ar = mt * 16 + lm;
      aoff[u][mt][0] = ar * 128 + ((kg ^ (ar & 7)) << 3);
      aoff[u][mt][1] = aoff[u][mt][0] + 64;
    }
#pragma unroll
    for (int nt = 0; nt < 2; ++nt) {
      int br = wn + nt * 16 + lm;
      boff[u][nt][0] = br * 128 + ((kg ^ (br & 7)) << 3);
      boff[u][nt][1] = boff[u][nt][0] + 64;
    }
  }

  STAGE(0, 0);
  STAGE(1, 1);
  int cur = 0;
  for (int j = 0; j < nk; ++j) {
    // stage(j) must be complete; stage(j+1) (12 loads/wave) may stay in flight
    if (j < nk - 1) asm volatile("s_waitcnt vmcnt(12)" ::: "memory");
    else            asm volatile("s_waitcnt vmcnt(0)" ::: "memory");
    asm volatile("s_waitcnt lgkmcnt(0)" ::: "memory");
    __builtin_amdgcn_s_barrier();
    if (j + 2 < nk) {
      int nb = cur + 2; if (nb >= 3) nb -= 3;
      STAGE(nb, j + 2);
    }
    const unsigned short* a0 = As + cur * 4096;
    const unsigned short* b0 = Bs + cur * 8192;
#pragma unroll
    for (int u = 0; u < 2; ++u) {
      s16x8 fa_h[2], fa_l[2], fb_h[2], fb_l[2];
#pragma unroll
      for (int mt = 0; mt < 2; ++mt) {
        fa_h[mt] = *(const s16x8*)(a0 + aoff[u][mt][0]);
        fa_l[mt] = *(const s16x8*)(a0 + aoff[u][mt][1]);
      }
#pragma unroll
      for (int nt = 0; nt < 2; ++nt) {
        fb_h[nt] = *(const s16x8*)(b0 + boff[u][nt][0]);
        fb_l[nt] = *(const s16x8*)(b0 + boff[u][nt][1]);
      }
#pragma unroll
      for (int mt = 0; mt < 2; ++mt)
#pragma unroll
        for (int nt = 0; nt < 2; ++nt) {
          acc[mt][nt] = __builtin_amdgcn_mfma_f32_16x16x32_bf16(fa_h[mt], fb_h[nt], acc[mt][nt], 0, 0, 0);
          acc[mt][nt] = __builtin_amdgcn_mfma_f32_16x16x32_bf16(fa_h[mt], fb_l[nt], acc[mt][nt], 0, 0, 0);
          acc[mt][nt] = __builtin_amdgcn_mfma_f32_16x16x32_bf16(fa_l[mt], fb_h[nt], acc[mt][nt], 0, 0, 0);
        }
    }
    cur = (cur == 2) ? 0 : cur + 1;
  }
#undef STAGE
}

// MODE 0: write split bf16 (Ch/Cl) with bias. MODE 1: fp32 C + bias. MODE 2: out scatter + bias.
template<int MODE>
__global__ __launch_bounds__(128)
void mfma_gemm(const unsigned short* __restrict__ Ah, const unsigned short* __restrict__ Al,
               const unsigned short* __restrict__ BTh, const unsigned short* __restrict__ BTl,
               const float* __restrict__ bias, float* __restrict__ Cf,
               unsigned short* __restrict__ Ch, unsigned short* __restrict__ Cl,
               int M, int N, int K, int gm, int gn)
{
  __shared__ unsigned short As[3 * 32 * 128];
  __shared__ unsigned short Bs[3 * 64 * 128];
  int bid = blockIdx.x;
  int xcd = bid & 7, w = bid >> 3;
  int bmi = w % gm, bni = xcd * (gn >> 3) + w / gm;
  long bm = (long)bmi * 32, bn = (long)bni * 64;
  f32x4 acc[2][2];
#pragma unroll
  for (int a = 0; a < 2; ++a)
#pragma unroll
    for (int b = 0; b < 2; ++b) acc[a][b] = (f32x4)0.f;
  gemm_core(Ah, Al, BTh, BTl, K, bm, bn, As, Bs, acc);

  const int tid = threadIdx.x, lane = tid & 63, wave = tid >> 6;
  const int wn = wave * 32;
#pragma unroll
  for (int nt = 0; nt < 2; ++nt) {
    int n = (int)bn + wn + nt * 16 + (lane & 15);
    float bv = bias[n];
#pragma unroll
    for (int mt = 0; mt < 2; ++mt) {
      long r0 = bm + mt * 16 + (lane >> 4) * 4;
#pragma unroll
      for (int r = 0; r < 4; ++r) {
        float v = acc[mt][nt][r] + bv;
        long R = r0 + r;
        if (MODE == 0) {
          unsigned short h_, l_; split2(v, h_, l_);
          Ch[R * N + n] = h_; Cl[R * N + n] = l_;
        } else if (MODE == 1) {
          Cf[R * N + n] = v;
        } else {
          long t = R >> 9, b = R & 511;
          Cf[(b * TT + t) * N + n] = v;
        }
      }
    }
  }
}

// ---------------- tick kernel (tau >= 1): GEMM + base + NLM epilogue ----------
template<int TAU>
__global__ __launch_bounds__(128)
void tick_mfma(const unsigned short* __restrict__ zh, const unsigned short* __restrict__ zl,
               const unsigned short* __restrict__ WTh, const unsigned short* __restrict__ WTl,
               const float* __restrict__ basep, const float* __restrict__ hist,
               float* __restrict__ histout,
               const float* __restrict__ w1, const float* __restrict__ b1,
               const float* __restrict__ w2, const float* __restrict__ b2,
               unsigned short* __restrict__ zho, unsigned short* __restrict__ zlo,
               unsigned short* __restrict__ zT)
{
  __shared__ unsigned short As[3 * 32 * 128];
  __shared__ unsigned short Bs[3 * 64 * 128];
  int bid = blockIdx.x;
  int xcd = bid & 7, w = bid >> 3;
  int bmi = w % 16, bni = xcd * 4 + w / 16;
  long bm = (long)bmi * 32, bn = (long)bni * 64;
  f32x4 acc[2][2];
#pragma unroll
  for (int a = 0; a < 2; ++a)
#pragma unroll
    for (int b = 0; b < 2; ++b) acc[a][b] = (f32x4)0.f;
  gemm_core(zh, zl, WTh, WTl, Dn, bm, bn, As, Bs, acc);

  const int tid = threadIdx.x, lane = tid & 63, wave = tid >> 6;
  const int wn = wave * 32;
#pragma unroll
  for (int nt = 0; nt < 2; ++nt) {
    const int d = (int)bn + wn + nt * 16 + (lane & 15);
    float w2v[Hh], b1v[Hh];
#pragma unroll
    for (int hh = 0; hh < Hh; ++hh) {
      w2v[hh] = w2[hh * Dn + d];
      b1v[hh] = b1[hh * Dn + d];
    }
    const float b2v = b2[d];
#pragma unroll
    for (int mt = 0; mt < 2; ++mt) {
      const int b0 = (int)bm + mt * 16 + (lane >> 4) * 4;
      float pre[4], hacc[4][Hh];
#pragma unroll
      for (int r = 0; r < 4; ++r) {
        pre[r] = acc[mt][nt][r] + basep[(size_t)(b0 + r) * Dn + d];
#pragma unroll
        for (int hh = 0; hh < Hh; ++hh) hacc[r][hh] = b1v[hh];
      }
#pragma unroll
      for (int s = 0; s < TAU; ++s) {
        float wv[Hh];
#pragma unroll
        for (int hh = 0; hh < Hh; ++hh) wv[hh] = w1[((15 - TAU + s) * Hh + hh) * Dn + d];
#pragma unroll
        for (int r = 0; r < 4; ++r) {
          float psv = hist[(size_t)s * BD + (size_t)(b0 + r) * Dn + d];
#pragma unroll
          for (int hh = 0; hh < Hh; ++hh) hacc[r][hh] = fmaf(psv, wv[hh], hacc[r][hh]);
        }
      }
      {
        float wv[Hh];
#pragma unroll
        for (int hh = 0; hh < Hh; ++hh) wv[hh] = w1[(15 * Hh + hh) * Dn + d];
#pragma unroll
        for (int r = 0; r < 4; ++r)
#pragma unroll
          for (int hh = 0; hh < Hh; ++hh) hacc[r][hh] = fmaf(pre[r], wv[hh], hacc[r][hh]);
      }
      u16x4 pack;
#pragma unroll
      for (int r = 0; r < 4; ++r) {
        histout[(size_t)(b0 + r) * Dn + d] = pre[r];
        float z = b2v;
#pragma unroll
        for (int hh = 0; hh < Hh; ++hh) z = fmaf(fmaxf(hacc[r][hh], 0.f), w2v[hh], z);
        unsigned short h_, l_; split2(z, h_, l_);
        zho[(size_t)(b0 + r) * Dn + d] = h_;
        zlo[(size_t)(b0 + r) * Dn + d] = l_;
        pack[r] = f2bf(z);
      }
      *(u16x4*)&zT[(size_t)d * Bsz + b0] = pack;
    }
  }
}

// ---------------- tick 0: pre = base + q, NLM single term --------------------
__global__ __launch_bounds__(256)
void tick0_kernel(const float* __restrict__ basep, const float* __restrict__ q,
                  float* __restrict__ histout,
                  const float* __restrict__ w1, const float* __restrict__ b1,
                  const float* __restrict__ w2, const float* __restrict__ b2,
                  unsigned short* __restrict__ zho, unsigned short* __restrict__ zlo,
                  unsigned short* __restrict__ zT)
{
  int g = blockIdx.x * 256 + threadIdx.x;
  int b = g >> 8;
  int d0 = (g & 255) * 8;
#pragma unroll
  for (int k = 0; k < 8; ++k) {
    int d = d0 + k;
    float pre = basep[(size_t)b * Dn + d] + q[d];
    histout[(size_t)b * Dn + d] = pre;
    float z = b2[d];
#pragma unroll
    for (int hh = 0; hh < Hh; ++hh) {
      float h = fmaf(pre, w1[(15 * Hh + hh) * Dn + d], b1[hh * Dn + d]);
      z = fmaf(fmaxf(h, 0.f), w2[hh * Dn + d], z);
    }
    unsigned short h_, l_; split2(z, h_, l_);
    zho[(size_t)b * Dn + d] = h_;
    zlo[(size_t)b * Dn + d] = l_;
    zT[(size_t)d * Bsz + b] = f2bf(z);
  }
}

// ---------------- batched sync: S for all ticks, both sets -------------------
__global__ __launch_bounds__(512)
void sync_kernel(const unsigned short* __restrict__ zT,
                 const int* __restrict__ pairs0, const int* __restrict__ pairs1,
                 const float* __restrict__ decay0, const float* __restrict__ decay1,
                 unsigned short* __restrict__ Sh0, unsigned short* __restrict__ Sl0,
                 unsigned short* __restrict__ Sh1, unsigned short* __restrict__ Sl1)
{
  __shared__ float Ls[8][8][65];
  const int set = blockIdx.y;
  const int* pairs = set ? pairs1 : pairs0;
  const float* decay = set ? decay1 : decay0;
  unsigned short* Sh = set ? Sh1 : Sh0;
  unsigned short* Sl = set ? Sl1 : Sl0;
  const int tid = threadIdx.x;
  const int lb = tid & 63, pl = tid >> 6;
  const int p = blockIdx.x * 8 + pl;
  const int i = pairs[2 * p], j = pairs[2 * p + 1];
  const float r = expf(-fabsf(decay[p]));
  const int pb = tid & 7, bb2 = tid >> 3;
  for (int bb = 0; bb < 8; ++bb) {
    int b = bb * 64 + lb;
    float S = 0.f, St[8];
#pragma unroll
    for (int t = 0; t < 8; ++t) {
      float zi = bf2f(zT[(size_t)t * BD + (size_t)i * Bsz + b]);
      float zj = bf2f(zT[(size_t)t * BD + (size_t)j * Bsz + b]);
      S = fmaf(S, r, zi * zj);
      St[t] = S;
    }
#pragma unroll
    for (int t = 0; t < 8; ++t) Ls[pl][t][lb] = St[t];
    __syncthreads();
#pragma unroll
    for (int t = 0; t < 8; ++t) {
      float v = Ls[pb][t][bb2];
      unsigned short h_, l_; split2(v, h_, l_);
      size_t off = ((size_t)t * Bsz + bb * 64 + bb2) * Pn + blockIdx.x * 8 + pb;
      Sh[off] = h_; Sl[off] = l_;
    }
    __syncthreads();
  }
}

// ---------------- weight transpose + bf16x2 split: (K,N) -> h/l (N,K) --------
__global__ __launch_bounds__(256)
void transpose_split_kernel(const float* __restrict__ in, int ldin,
                            unsigned short* __restrict__ Th, unsigned short* __restrict__ Tl,
                            int K)
{
  __shared__ float T[64][65];
  int k0 = blockIdx.x * 64, n0 = blockIdx.y * 64;
  int tid = threadIdx.x;
  int r = tid >> 2, c0 = (tid & 3) * 16;
#pragma unroll
  for (int cc = 0; cc < 16; cc += 4) {
    float4 v = *(const float4*)(in + (size_t)(k0 + r) * ldin + n0 + c0 + cc);
    T[c0 + cc + 0][r] = v.x; T[c0 + cc + 1][r] = v.y;
    T[c0 + cc + 2][r] = v.z; T[c0 + cc + 3][r] = v.w;
  }
  __syncthreads();
  int n = tid >> 2, kc = (tid & 3) * 16;
#pragma unroll
  for (int kk = 0; kk < 16; ++kk) {
    float v = T[n][kc + kk];
    unsigned short h_, l_; split2(v, h_, l_);
    Th[(size_t)(n0 + n) * K + k0 + kc + kk] = h_;
    Tl[(size_t)(n0 + n) * K + k0 + kc + kk] = l_;
  }
}

// ---------------- elementwise split (x) --------------------------------------
__global__ __launch_bounds__(256)
void split_kernel(const float* __restrict__ x, unsigned short* __restrict__ xh,
                  unsigned short* __restrict__ xl, int n4)
{
  int i = blockIdx.x * 256 + threadIdx.x;
  if (i >= n4) return;
  float4 v = *(const float4*)(x + (size_t)i * 4);
  u16x4 h, l;
  unsigned short th, tl;
  split2(v.x, th, tl); h[0] = th; l[0] = tl;
  split2(v.y, th, tl); h[1] = th; l[1] = tl;
  split2(v.z, th, tl); h[2] = th; l[2] = tl;
  split2(v.w, th, tl); h[3] = th; l[3] = tl;
  *(u16x4*)(xh + (size_t)i * 4) = h;
  *(u16x4*)(xl + (size_t)i * 4) = l;
}

// ---------------- split-K matvec partials: part[kc][col] ---------------------
__global__ __launch_bounds__(256)
void matvec_part_kernel(const float* __restrict__ vec, const float* __restrict__ W,
                        float* __restrict__ part, int K, int N)
{
  __shared__ float red[4][64];
  const int tid = threadIdx.x;
  const int c = tid & 63, strip = tid >> 6;
  const int col = blockIdx.x * 64 + c;
  const int kpc = K / (gridDim.y * 4);
  const int k0 = (blockIdx.y * 4 + strip) * kpc;
  float acc = 0.f;
#pragma unroll 8
  for (int k = k0; k < k0 + kpc; ++k)
    acc = fmaf(vec[k], W[(size_t)k * N + col], acc);
  red[strip][c] = acc;
  __syncthreads();
  if (strip == 0)
    part[(size_t)blockIdx.y * N + col] = red[0][c] + red[1][c] + red[2][c] + red[3][c];
}

__global__ __launch_bounds__(256)
void reduce_q_kernel(const float* __restrict__ part, float* __restrict__ q, int N, int C)
{
  int d = blockIdx.x * 256 + threadIdx.x;
  if (d >= N) return;
  float s = 0.f;
  for (int c = 0; c < C; ++c) s += part[(size_t)c * N + d];
  q[d] = s;
}

extern "C" void kernel_launch(void* const* d_in, const int* in_sizes, int n_in,
                              void* d_out, int out_size, void* d_ws, size_t ws_size,
                              hipStream_t stream) {
  const float* x      = (const float*)d_in[0];
  const float* W_in   = (const float*)d_in[1];
  const float* b_in   = (const float*)d_in[2];
  const float* z0     = (const float*)d_in[3];
  const float* W_syn  = (const float*)d_in[4];
  const float* b_syn  = (const float*)d_in[5];
  const float* w1     = (const float*)d_in[6];
  const float* b1     = (const float*)d_in[7];
  const float* w2     = (const float*)d_in[8];
  const float* b2     = (const float*)d_in[9];
  const float* decay_out = (const float*)d_in[10];
  const float* decay_act = (const float*)d_in[11];
  const float* W_out  = (const float*)d_in[12];
  const float* b_out  = (const float*)d_in[13];
  const float* W_act  = (const float*)d_in[14];
  const float* b_act  = (const float*)d_in[15];
  const int* pairs_out = (const int*)d_in[16];
  const int* pairs_act = (const int*)d_in[17];

  char* W = (char*)d_ws;
  auto alloc = [&](size_t bytes) { char* p = W; W += (bytes + 255) & ~255ull; return p; };
  unsigned short* WtTh = (unsigned short*)alloc((size_t)Dn * Dn * 2);
  unsigned short* WtTl = (unsigned short*)alloc((size_t)Dn * Dn * 2);
  unsigned short* WbTh = (unsigned short*)alloc((size_t)Dn * Dn * 2);
  unsigned short* WbTl = (unsigned short*)alloc((size_t)Dn * Dn * 2);
  unsigned short* WinTh = (unsigned short*)alloc((size_t)Dn * DIN * 2);
  unsigned short* WinTl = (unsigned short*)alloc((size_t)Dn * DIN * 2);
  unsigned short* WoTh = (unsigned short*)alloc((size_t)DOUT * Pn * 2);
  unsigned short* WoTl = (unsigned short*)alloc((size_t)DOUT * Pn * 2);
  unsigned short* WaTh = (unsigned short*)alloc((size_t)DOUT * Pn * 2);
  unsigned short* WaTl = (unsigned short*)alloc((size_t)DOUT * Pn * 2);
  unsigned short* xh = (unsigned short*)alloc((size_t)Bsz * DIN * 2);
  unsigned short* xl = (unsigned short*)alloc((size_t)Bsz * DIN * 2);
  unsigned short* fh = (unsigned short*)alloc((size_t)BD * 2);
  unsigned short* fl = (unsigned short*)alloc((size_t)BD * 2);
  float* q     = (float*)alloc(Dn * 4);
  float* qpart = (float*)alloc(8 * Dn * 4);
  float* base  = (float*)alloc((size_t)BD * 4);
  float* hist  = (float*)alloc((size_t)TT * BD * 4);
  unsigned short* zbh[2], *zbl[2];
  zbh[0] = (unsigned short*)alloc((size_t)BD * 2);
  zbl[0] = (unsigned short*)alloc((size_t)BD * 2);
  zbh[1] = (unsigned short*)alloc((size_t)BD * 2);
  zbl[1] = (unsigned short*)alloc((size_t)BD * 2);
  unsigned short* zT = (unsigned short*)alloc((size_t)TT * BD * 2);
  // S buffers alias the (dead-after-base-GEMM) WbT region: 4MB each
  unsigned short* Sh0 = WbTh;
  unsigned short* Sl0 = WbTh + (size_t)TT * Bsz * Pn;
  unsigned short* Sh1 = WbTl;
  unsigned short* Sl1 = WbTl + (size_t)TT * Bsz * Pn;

  float* outy = (float*)d_out;
  float* outq = outy + (size_t)Bsz * TT * DOUT;

  dim3 blk(256);
  dim3 blk128(128);
  // weight prep
  transpose_split_kernel<<<dim3(32, 32), blk, 0, stream>>>(W_syn, Dn, WtTh, WtTl, Dn);
  transpose_split_kernel<<<dim3(32, 32), blk, 0, stream>>>(W_syn + (size_t)Dn * Dn, Dn, WbTh, WbTl, Dn);
  transpose_split_kernel<<<dim3(8, 32), blk, 0, stream>>>(W_in, Dn, WinTh, WinTl, DIN);
  transpose_split_kernel<<<dim3(8, 8), blk, 0, stream>>>(W_out, DOUT, WoTh, WoTl, Pn);
  transpose_split_kernel<<<dim3(8, 8), blk, 0, stream>>>(W_act, DOUT, WaTh, WaTl, Pn);
  split_kernel<<<dim3(Bsz * DIN / 1024), blk, 0, stream>>>(x, xh, xl, Bsz * DIN / 4);
  // q = z0 @ W_syn_top via split-K partials + reduce
  matvec_part_kernel<<<dim3(Dn / 64, 8), blk, 0, stream>>>(z0, W_syn, qpart, Dn, Dn);
  reduce_q_kernel<<<dim3(Dn / 256), blk, 0, stream>>>(qpart, q, Dn, 8);
  // feats = x @ W_in + b_in (split output; bias folded in)
  mfma_gemm<0><<<dim3(512), blk128, 0, stream>>>(xh, xl, WinTh, WinTl, b_in, nullptr, fh, fl,
                                                 Bsz, Dn, DIN, 16, 32);
  // base = feats @ W_syn_bot + b_syn
  mfma_gemm<1><<<dim3(512), blk128, 0, stream>>>(fh, fl, WbTh, WbTl, b_syn, base, nullptr, nullptr,
                                                 Bsz, Dn, Dn, 16, 32);
  // tick 0
  tick0_kernel<<<dim3(512), blk, 0, stream>>>(base, q, hist, w1, b1, w2, b2,
                                              zbh[0], zbl[0], zT);
  // ticks 1..7
  for (int tau = 1; tau < TT; ++tau) {
    const unsigned short* zih = zbh[(tau + 1) & 1];
    const unsigned short* zil = zbl[(tau + 1) & 1];
    unsigned short* zoh = zbh[tau & 1];
    unsigned short* zol = zbl[tau & 1];
    float* ho = hist + (size_t)tau * BD;
    unsigned short* zTo = zT + (size_t)tau * BD;
    switch (tau) {
      case 1: tick_mfma<1><<<dim3(512), blk128, 0, stream>>>(zih, zil, WtTh, WtTl, base, hist, ho, w1, b1, w2, b2, zoh, zol, zTo); break;
      case 2: tick_mfma<2><<<dim3(512), blk128, 0, stream>>>(zih, zil, WtTh, WtTl, base, hist, ho, w1, b1, w2, b2, zoh, zol, zTo); break;
      case 3: tick_mfma<3><<<dim3(512), blk128, 0, stream>>>(zih, zil, WtTh, WtTl, base, hist, ho, w1, b1, w2, b2, zoh, zol, zTo); break;
      case 4: tick_mfma<4><<<dim3(512), blk128, 0, stream>>>(zih, zil, WtTh, WtTl, base, hist, ho, w1, b1, w2, b2, zoh, zol, zTo); break;
      case 5: tick_mfma<5><<<dim3(512), blk128, 0, stream>>>(zih, zil, WtTh, WtTl, base, hist, ho, w1, b1, w2, b2, zoh, zol, zTo); break;
      case 6: tick_mfma<6><<<dim3(512), blk128, 0, stream>>>(zih, zil, WtTh, WtTl, base, hist, ho, w1, b1, w2, b2, zoh, zol, zTo); break;
      case 7: tick_mfma<7><<<dim3(512), blk128, 0, stream>>>(zih, zil, WtTh, WtTl, base, hist, ho, w1, b1, w2, b2, zoh, zol, zTo); break;
    }
  }
  // batched sync for both sets
  sync_kernel<<<dim3(Pn / 8, 2), dim3(512), 0, stream>>>(zT, pairs_out, pairs_act,
                                                         decay_out, decay_act,
                                                         Sh0, Sl0, Sh1, Sl1);
  // output GEMMs over all (t, b) rows
  mfma_gemm<2><<<dim3(1024), blk128, 0, stream>>>(Sh0, Sl0, WoTh, WoTl, b_out, outy, nullptr, nullptr,
                                                  TT * Bsz, DOUT, Pn, 128, 8);
  mfma_gemm<2><<<dim3(1024), blk128, 0, stream>>>(Sh1, Sl1, WaTh, WaTl, b_act, outq, nullptr, nullptr,
                                                  TT * Bsz, DOUT, Pn, 128, 8);
}

// Round 9
// 317.742 us; speedup vs baseline: 1.4750x; 1.4750x over previous
//
#include <hip/hip_runtime.h>
#include <math.h>

#define Bsz 512
#define TT 8
#define Dn 2048
#define DIN 512
#define Hh 4
#define Pn 512
#define DOUT 512
#define BD (Bsz*Dn)

typedef __attribute__((ext_vector_type(8))) short s16x8;
typedef __attribute__((ext_vector_type(4))) float f32x4;
typedef __attribute__((ext_vector_type(4))) unsigned short u16x4;

__device__ __forceinline__ unsigned short f2bf(float f) {
  unsigned int u = __float_as_uint(f);
  unsigned int r = (u + 0x7fffu + ((u >> 16) & 1u)) >> 16;
  return (unsigned short)r;
}
__device__ __forceinline__ float bf2f(unsigned short h) {
  return __uint_as_float(((unsigned int)h) << 16);
}
__device__ __forceinline__ void split2(float x, unsigned short& h, unsigned short& l) {
  h = f2bf(x);
  float r = x - bf2f(h);
  l = f2bf(r);
}

// async global->LDS, 16B per lane, LDS dest = wave-uniform base + lane*16
#define GLOAD16(g, l) __builtin_amdgcn_global_load_lds( \
    (const __attribute__((address_space(1))) unsigned int*)(g), \
    (__attribute__((address_space(3))) unsigned int*)(l), 16, 0, 0)

// ---------------- MFMA GEMM core (r9: 8-wave dual K-parity pipelines) --------
// A (M,K) h/l bf16 row-major; B as BT h/l (N,K) row-major.
// 64x64 block tile, 512 threads = 2 groups (K-parity) x 4 waves (32x32
// quadrants). BK=32/step; group g owns steps s=2i+g with its own 4-buf LDS
// ring and its own counted vmcnt; one workgroup barrier per iter (both groups
// execute the same count). Final: group1 dumps acc to LDS, group0 adds and
// runs the epilogue. Rationale (r8 post-mortem): 32x32 wave tiles need >=8
// waves/CU; with only 256 64x64 tiles this is the way to get both.
// LDS: shorts [0..32768) = A bufs 8x4096, [32768..65536) = B bufs 8x4096.
__device__ __forceinline__ void gemm_core(
    const unsigned short* __restrict__ Ah, const unsigned short* __restrict__ Al,
    const unsigned short* __restrict__ BTh, const unsigned short* __restrict__ BTl,
    int K, long arow0, long brow0,
    unsigned short* LDS, f32x4 acc[2][2], int g, int qw)
{
  const int tid = threadIdx.x;
  const int lane = tid & 63;
  // staging: this wave covers A rows [qw*16,+16) and B rows [qw*16,+16),
  // 2 gloads each. Lane l -> row +(l>>3), slot (l&7): part=slot>>2,
  // kg_store=(slot&3)^(row&3)  (swizzle folded into the global address).
  const int l3 = lane >> 3, slot = lane & 7, part = slot >> 2;
  const unsigned short* gsrc[4];
  int ldst[4];
#pragma unroll
  for (int t = 0; t < 2; ++t) {
    int rb = qw * 16 + t * 8;
    int row = rb + l3;
    int ko = ((slot & 3) ^ (row & 3)) << 3;
    gsrc[t]     = (part ? Al : Ah) + (size_t)(arow0 + row) * K + ko;
    ldst[t]     = rb * 64;
    gsrc[2 + t] = (part ? BTl : BTh) + (size_t)(brow0 + row) * K + ko;
    ldst[2 + t] = 32768 + rb * 64;
  }

  const int nI = K >> 6;   // steps per group (K/32/2); >= 8 at all call sites

#define STAGE(ring, i_)                                              \
  {                                                                  \
    const size_t kb = ((size_t)(2 * (i_) + g)) << 5;                 \
    unsigned short* base = LDS + (g * 4 + (ring)) * 4096;            \
    GLOAD16(gsrc[0] + kb, base + ldst[0]);                           \
    GLOAD16(gsrc[1] + kb, base + ldst[1]);                           \
    GLOAD16(gsrc[2] + kb, base + ldst[2]);                           \
    GLOAD16(gsrc[3] + kb, base + ldst[3]);                           \
  }

  // fragment LDS offsets (shorts); quadrant (qw&1)=M half, (qw>>1)=N half
  const int wm = (qw & 1) * 32, wn = (qw >> 1) * 32;
  const int lm = lane & 15, kg4 = lane >> 4;
  int aoh[2], bofh[2];
#pragma unroll
  for (int mt = 0; mt < 2; ++mt) {
    int ar = wm + mt * 16 + lm;
    aoh[mt] = ar * 64 + ((kg4 ^ (ar & 3)) << 3);
  }
#pragma unroll
  for (int nt = 0; nt < 2; ++nt) {
    int br = wn + nt * 16 + lm;
    bofh[nt] = br * 64 + ((kg4 ^ (br & 3)) << 3);
  }

  STAGE(0, 0);
  STAGE(1, 1);
  for (int i = 0; i < nI; ++i) {
    if (i + 1 < nI) asm volatile("s_waitcnt vmcnt(4)" ::: "memory");
    else            asm volatile("s_waitcnt vmcnt(0)" ::: "memory");
    __builtin_amdgcn_s_barrier();
    if (i + 2 < nI) STAGE((i + 2) & 3, i + 2);
    const unsigned short* ab = LDS + (g * 4 + (i & 3)) * 4096;
    const unsigned short* bb = ab + 32768;
    s16x8 fah[2], fal[2], fbh[2], fbl[2];
#pragma unroll
    for (int mt = 0; mt < 2; ++mt) {
      fah[mt] = *(const s16x8*)(ab + aoh[mt]);
      fal[mt] = *(const s16x8*)(ab + aoh[mt] + 32);
    }
#pragma unroll
    for (int nt = 0; nt < 2; ++nt) {
      fbh[nt] = *(const s16x8*)(bb + bofh[nt]);
      fbl[nt] = *(const s16x8*)(bb + bofh[nt] + 32);
    }
#pragma unroll
    for (int mt = 0; mt < 2; ++mt)
#pragma unroll
      for (int nt = 0; nt < 2; ++nt) {
        acc[mt][nt] = __builtin_amdgcn_mfma_f32_16x16x32_bf16(fah[mt], fbh[nt], acc[mt][nt], 0, 0, 0);
        acc[mt][nt] = __builtin_amdgcn_mfma_f32_16x16x32_bf16(fah[mt], fbl[nt], acc[mt][nt], 0, 0, 0);
        acc[mt][nt] = __builtin_amdgcn_mfma_f32_16x16x32_bf16(fal[mt], fbh[nt], acc[mt][nt], 0, 0, 0);
      }
  }
#undef STAGE

  // cross-group reduction: group1 -> LDS (pad 17 to avoid bank conflicts),
  // group0 adds. Both groups execute both barriers (count-matched).
  __builtin_amdgcn_s_barrier();
  float* fred = (float*)LDS;
  const int ridx = (qw * 64 + lane) * 17;
  if (g == 1) {
#pragma unroll
    for (int mt = 0; mt < 2; ++mt)
#pragma unroll
      for (int nt = 0; nt < 2; ++nt)
#pragma unroll
        for (int r = 0; r < 4; ++r)
          fred[ridx + (mt * 2 + nt) * 4 + r] = acc[mt][nt][r];
  }
  __builtin_amdgcn_s_barrier();
  if (g == 0) {
#pragma unroll
    for (int mt = 0; mt < 2; ++mt)
#pragma unroll
      for (int nt = 0; nt < 2; ++nt)
#pragma unroll
        for (int r = 0; r < 4; ++r)
          acc[mt][nt][r] += fred[ridx + (mt * 2 + nt) * 4 + r];
  }
}

// MODE 0: split bf16 out + bias. MODE 1: fp32 out + bias. MODE 2: out scatter + bias.
template<int MODE>
__global__ __launch_bounds__(512, 1)
void mfma_gemm(const unsigned short* __restrict__ Ah, const unsigned short* __restrict__ Al,
               const unsigned short* __restrict__ BTh, const unsigned short* __restrict__ BTl,
               const float* __restrict__ bias, float* __restrict__ Cf,
               unsigned short* __restrict__ Ch, unsigned short* __restrict__ Cl,
               int M, int N, int K, int gm, int gn)
{
  __shared__ unsigned short LDS[65536];
  int bid = blockIdx.x;
  int xcd = bid & 7, w = bid >> 3;
  int bmi = w % gm, bni = xcd * (gn >> 3) + w / gm;
  long bm = (long)bmi * 64, bn = (long)bni * 64;
  const int tid = threadIdx.x, lane = tid & 63, wave = tid >> 6;
  const int g = wave >> 2, qw = wave & 3;
  f32x4 acc[2][2];
#pragma unroll
  for (int a = 0; a < 2; ++a)
#pragma unroll
    for (int b = 0; b < 2; ++b) acc[a][b] = (f32x4)0.f;
  gemm_core(Ah, Al, BTh, BTl, K, bm, bn, LDS, acc, g, qw);
  if (g == 1) return;

  const int wm = (qw & 1) * 32, wn = (qw >> 1) * 32;
#pragma unroll
  for (int nt = 0; nt < 2; ++nt) {
    int n = (int)bn + wn + nt * 16 + (lane & 15);
    float bv = bias[n];
#pragma unroll
    for (int mt = 0; mt < 2; ++mt) {
      long r0 = bm + wm + mt * 16 + (lane >> 4) * 4;
#pragma unroll
      for (int r = 0; r < 4; ++r) {
        float v = acc[mt][nt][r] + bv;
        long R = r0 + r;
        if (MODE == 0) {
          unsigned short h_, l_; split2(v, h_, l_);
          Ch[R * N + n] = h_; Cl[R * N + n] = l_;
        } else if (MODE == 1) {
          Cf[R * N + n] = v;
        } else {
          long t = R >> 9, b = R & 511;
          Cf[(b * TT + t) * N + n] = v;
        }
      }
    }
  }
}

// ---------------- tick kernel (tau >= 1): GEMM + base + NLM epilogue ----------
template<int TAU>
__global__ __launch_bounds__(512, 1)
void tick_mfma(const unsigned short* __restrict__ zh, const unsigned short* __restrict__ zl,
               const unsigned short* __restrict__ WTh, const unsigned short* __restrict__ WTl,
               const float* __restrict__ basep, const float* __restrict__ hist,
               float* __restrict__ histout,
               const float* __restrict__ w1, const float* __restrict__ b1,
               const float* __restrict__ w2, const float* __restrict__ b2,
               unsigned short* __restrict__ zho, unsigned short* __restrict__ zlo,
               unsigned short* __restrict__ zT)
{
  __shared__ unsigned short LDS[65536];
  int bid = blockIdx.x;
  int xcd = bid & 7, w = bid >> 3;
  int bmi = w % 8, bni = xcd * 4 + w / 8;
  long bm = (long)bmi * 64, bn = (long)bni * 64;
  const int tid = threadIdx.x, lane = tid & 63, wave = tid >> 6;
  const int g = wave >> 2, qw = wave & 3;
  f32x4 acc[2][2];
#pragma unroll
  for (int a = 0; a < 2; ++a)
#pragma unroll
    for (int b = 0; b < 2; ++b) acc[a][b] = (f32x4)0.f;
  gemm_core(zh, zl, WTh, WTl, Dn, bm, bn, LDS, acc, g, qw);
  if (g == 1) return;

  const int wm = (qw & 1) * 32, wn = (qw >> 1) * 32;
#pragma unroll
  for (int nt = 0; nt < 2; ++nt) {
    const int d = (int)bn + wn + nt * 16 + (lane & 15);
    float w2v[Hh], b1v[Hh];
#pragma unroll
    for (int hh = 0; hh < Hh; ++hh) {
      w2v[hh] = w2[hh * Dn + d];
      b1v[hh] = b1[hh * Dn + d];
    }
    const float b2v = b2[d];
#pragma unroll
    for (int mt = 0; mt < 2; ++mt) {
      const int b0 = (int)bm + wm + mt * 16 + (lane >> 4) * 4;
      float pre[4], hacc[4][Hh];
#pragma unroll
      for (int r = 0; r < 4; ++r) {
        pre[r] = acc[mt][nt][r] + basep[(size_t)(b0 + r) * Dn + d];
#pragma unroll
        for (int hh = 0; hh < Hh; ++hh) hacc[r][hh] = b1v[hh];
      }
#pragma unroll
      for (int s = 0; s < TAU; ++s) {
        float wv[Hh];
#pragma unroll
        for (int hh = 0; hh < Hh; ++hh) wv[hh] = w1[((15 - TAU + s) * Hh + hh) * Dn + d];
#pragma unroll
        for (int r = 0; r < 4; ++r) {
          float psv = hist[(size_t)s * BD + (size_t)(b0 + r) * Dn + d];
#pragma unroll
          for (int hh = 0; hh < Hh; ++hh) hacc[r][hh] = fmaf(psv, wv[hh], hacc[r][hh]);
        }
      }
      {
        float wv[Hh];
#pragma unroll
        for (int hh = 0; hh < Hh; ++hh) wv[hh] = w1[(15 * Hh + hh) * Dn + d];
#pragma unroll
        for (int r = 0; r < 4; ++r)
#pragma unroll
          for (int hh = 0; hh < Hh; ++hh) hacc[r][hh] = fmaf(pre[r], wv[hh], hacc[r][hh]);
      }
      u16x4 pack;
#pragma unroll
      for (int r = 0; r < 4; ++r) {
        histout[(size_t)(b0 + r) * Dn + d] = pre[r];
        float z = b2v;
#pragma unroll
        for (int hh = 0; hh < Hh; ++hh) z = fmaf(fmaxf(hacc[r][hh], 0.f), w2v[hh], z);
        unsigned short h_, l_; split2(z, h_, l_);
        zho[(size_t)(b0 + r) * Dn + d] = h_;
        zlo[(size_t)(b0 + r) * Dn + d] = l_;
        pack[r] = f2bf(z);
      }
      *(u16x4*)&zT[(size_t)d * Bsz + b0] = pack;
    }
  }
}

// ---------------- tick 0: pre = base + q, NLM single term --------------------
__global__ __launch_bounds__(256)
void tick0_kernel(const float* __restrict__ basep, const float* __restrict__ q,
                  float* __restrict__ histout,
                  const float* __restrict__ w1, const float* __restrict__ b1,
                  const float* __restrict__ w2, const float* __restrict__ b2,
                  unsigned short* __restrict__ zho, unsigned short* __restrict__ zlo,
                  unsigned short* __restrict__ zT)
{
  int g = blockIdx.x * 256 + threadIdx.x;
  int b = g >> 8;
  int d0 = (g & 255) * 8;
#pragma unroll
  for (int k = 0; k < 8; ++k) {
    int d = d0 + k;
    float pre = basep[(size_t)b * Dn + d] + q[d];
    histout[(size_t)b * Dn + d] = pre;
    float z = b2[d];
#pragma unroll
    for (int hh = 0; hh < Hh; ++hh) {
      float h = fmaf(pre, w1[(15 * Hh + hh) * Dn + d], b1[hh * Dn + d]);
      z = fmaf(fmaxf(h, 0.f), w2[hh * Dn + d], z);
    }
    unsigned short h_, l_; split2(z, h_, l_);
    zho[(size_t)b * Dn + d] = h_;
    zlo[(size_t)b * Dn + d] = l_;
    zT[(size_t)d * Bsz + b] = f2bf(z);
  }
}

// ---------------- batched sync: S for all ticks, both sets -------------------
__global__ __launch_bounds__(512)
void sync_kernel(const unsigned short* __restrict__ zT,
                 const int* __restrict__ pairs0, const int* __restrict__ pairs1,
                 const float* __restrict__ decay0, const float* __restrict__ decay1,
                 unsigned short* __restrict__ Sh0, unsigned short* __restrict__ Sl0,
                 unsigned short* __restrict__ Sh1, unsigned short* __restrict__ Sl1)
{
  __shared__ float Ls[8][8][65];
  const int set = blockIdx.y;
  const int* pairs = set ? pairs1 : pairs0;
  const float* decay = set ? decay1 : decay0;
  unsigned short* Sh = set ? Sh1 : Sh0;
  unsigned short* Sl = set ? Sl1 : Sl0;
  const int tid = threadIdx.x;
  const int lb = tid & 63, pl = tid >> 6;
  const int p = blockIdx.x * 8 + pl;
  const int i = pairs[2 * p], j = pairs[2 * p + 1];
  const float r = expf(-fabsf(decay[p]));
  const int pb = tid & 7, bb2 = tid >> 3;
  for (int bb = 0; bb < 8; ++bb) {
    int b = bb * 64 + lb;
    float S = 0.f, St[8];
#pragma unroll
    for (int t = 0; t < 8; ++t) {
      float zi = bf2f(zT[(size_t)t * BD + (size_t)i * Bsz + b]);
      float zj = bf2f(zT[(size_t)t * BD + (size_t)j * Bsz + b]);
      S = fmaf(S, r, zi * zj);
      St[t] = S;
    }
#pragma unroll
    for (int t = 0; t < 8; ++t) Ls[pl][t][lb] = St[t];
    __syncthreads();
#pragma unroll
    for (int t = 0; t < 8; ++t) {
      float v = Ls[pb][t][bb2];
      unsigned short h_, l_; split2(v, h_, l_);
      size_t off = ((size_t)t * Bsz + bb * 64 + bb2) * Pn + blockIdx.x * 8 + pb;
      Sh[off] = h_; Sl[off] = l_;
    }
    __syncthreads();
  }
}

// ---------------- weight transpose + bf16x2 split: (K,N) -> h/l (N,K) --------
__global__ __launch_bounds__(256)
void transpose_split_kernel(const float* __restrict__ in, int ldin,
                            unsigned short* __restrict__ Th, unsigned short* __restrict__ Tl,
                            int K)
{
  __shared__ float T[64][65];
  int k0 = blockIdx.x * 64, n0 = blockIdx.y * 64;
  int tid = threadIdx.x;
  int r = tid >> 2, c0 = (tid & 3) * 16;
#pragma unroll
  for (int cc = 0; cc < 16; cc += 4) {
    float4 v = *(const float4*)(in + (size_t)(k0 + r) * ldin + n0 + c0 + cc);
    T[c0 + cc + 0][r] = v.x; T[c0 + cc + 1][r] = v.y;
    T[c0 + cc + 2][r] = v.z; T[c0 + cc + 3][r] = v.w;
  }
  __syncthreads();
  int n = tid >> 2, kc = (tid & 3) * 16;
#pragma unroll
  for (int kk = 0; kk < 16; ++kk) {
    float v = T[n][kc + kk];
    unsigned short h_, l_; split2(v, h_, l_);
    Th[(size_t)(n0 + n) * K + k0 + kc + kk] = h_;
    Tl[(size_t)(n0 + n) * K + k0 + kc + kk] = l_;
  }
}

// ---------------- elementwise split (x) --------------------------------------
__global__ __launch_bounds__(256)
void split_kernel(const float* __restrict__ x, unsigned short* __restrict__ xh,
                  unsigned short* __restrict__ xl, int n4)
{
  int i = blockIdx.x * 256 + threadIdx.x;
  if (i >= n4) return;
  float4 v = *(const float4*)(x + (size_t)i * 4);
  u16x4 h, l;
  unsigned short th, tl;
  split2(v.x, th, tl); h[0] = th; l[0] = tl;
  split2(v.y, th, tl); h[1] = th; l[1] = tl;
  split2(v.z, th, tl); h[2] = th; l[2] = tl;
  split2(v.w, th, tl); h[3] = th; l[3] = tl;
  *(u16x4*)(xh + (size_t)i * 4) = h;
  *(u16x4*)(xl + (size_t)i * 4) = l;
}

// ---------------- split-K matvec partials: part[kc][col] ---------------------
__global__ __launch_bounds__(256)
void matvec_part_kernel(const float* __restrict__ vec, const float* __restrict__ W,
                        float* __restrict__ part, int K, int N)
{
  __shared__ float red[4][64];
  const int tid = threadIdx.x;
  const int c = tid & 63, strip = tid >> 6;
  const int col = blockIdx.x * 64 + c;
  const int kpc = K / (gridDim.y * 4);
  const int k0 = (blockIdx.y * 4 + strip) * kpc;
  float acc = 0.f;
#pragma unroll 8
  for (int k = k0; k < k0 + kpc; ++k)
    acc = fmaf(vec[k], W[(size_t)k * N + col], acc);
  red[strip][c] = acc;
  __syncthreads();
  if (strip == 0)
    part[(size_t)blockIdx.y * N + col] = red[0][c] + red[1][c] + red[2][c] + red[3][c];
}

__global__ __launch_bounds__(256)
void reduce_q_kernel(const float* __restrict__ part, float* __restrict__ q, int N, int C)
{
  int d = blockIdx.x * 256 + threadIdx.x;
  if (d >= N) return;
  float s = 0.f;
  for (int c = 0; c < C; ++c) s += part[(size_t)c * N + d];
  q[d] = s;
}

extern "C" void kernel_launch(void* const* d_in, const int* in_sizes, int n_in,
                              void* d_out, int out_size, void* d_ws, size_t ws_size,
                              hipStream_t stream) {
  const float* x      = (const float*)d_in[0];
  const float* W_in   = (const float*)d_in[1];
  const float* b_in   = (const float*)d_in[2];
  const float* z0     = (const float*)d_in[3];
  const float* W_syn  = (const float*)d_in[4];
  const float* b_syn  = (const float*)d_in[5];
  const float* w1     = (const float*)d_in[6];
  const float* b1     = (const float*)d_in[7];
  const float* w2     = (const float*)d_in[8];
  const float* b2     = (const float*)d_in[9];
  const float* decay_out = (const float*)d_in[10];
  const float* decay_act = (const float*)d_in[11];
  const float* W_out  = (const float*)d_in[12];
  const float* b_out  = (const float*)d_in[13];
  const float* W_act  = (const float*)d_in[14];
  const float* b_act  = (const float*)d_in[15];
  const int* pairs_out = (const int*)d_in[16];
  const int* pairs_act = (const int*)d_in[17];

  char* W = (char*)d_ws;
  auto alloc = [&](size_t bytes) { char* p = W; W += (bytes + 255) & ~255ull; return p; };
  unsigned short* WtTh = (unsigned short*)alloc((size_t)Dn * Dn * 2);
  unsigned short* WtTl = (unsigned short*)alloc((size_t)Dn * Dn * 2);
  unsigned short* WbTh = (unsigned short*)alloc((size_t)Dn * Dn * 2);
  unsigned short* WbTl = (unsigned short*)alloc((size_t)Dn * Dn * 2);
  unsigned short* WinTh = (unsigned short*)alloc((size_t)Dn * DIN * 2);
  unsigned short* WinTl = (unsigned short*)alloc((size_t)Dn * DIN * 2);
  unsigned short* WoTh = (unsigned short*)alloc((size_t)DOUT * Pn * 2);
  unsigned short* WoTl = (unsigned short*)alloc((size_t)DOUT * Pn * 2);
  unsigned short* WaTh = (unsigned short*)alloc((size_t)DOUT * Pn * 2);
  unsigned short* WaTl = (unsigned short*)alloc((size_t)DOUT * Pn * 2);
  unsigned short* xh = (unsigned short*)alloc((size_t)Bsz * DIN * 2);
  unsigned short* xl = (unsigned short*)alloc((size_t)Bsz * DIN * 2);
  unsigned short* fh = (unsigned short*)alloc((size_t)BD * 2);
  unsigned short* fl = (unsigned short*)alloc((size_t)BD * 2);
  float* q     = (float*)alloc(Dn * 4);
  float* qpart = (float*)alloc(8 * Dn * 4);
  float* base  = (float*)alloc((size_t)BD * 4);
  float* hist  = (float*)alloc((size_t)TT * BD * 4);
  unsigned short* zbh[2], *zbl[2];
  zbh[0] = (unsigned short*)alloc((size_t)BD * 2);
  zbl[0] = (unsigned short*)alloc((size_t)BD * 2);
  zbh[1] = (unsigned short*)alloc((size_t)BD * 2);
  zbl[1] = (unsigned short*)alloc((size_t)BD * 2);
  unsigned short* zT = (unsigned short*)alloc((size_t)TT * BD * 2);
  // S buffers alias the (dead-after-base-GEMM) WbT region: 4MB each
  unsigned short* Sh0 = WbTh;
  unsigned short* Sl0 = WbTh + (size_t)TT * Bsz * Pn;
  unsigned short* Sh1 = WbTl;
  unsigned short* Sl1 = WbTl + (size_t)TT * Bsz * Pn;

  float* outy = (float*)d_out;
  float* outq = outy + (size_t)Bsz * TT * DOUT;

  dim3 blk(256);
  dim3 blk512(512);
  // weight prep
  transpose_split_kernel<<<dim3(32, 32), blk, 0, stream>>>(W_syn, Dn, WtTh, WtTl, Dn);
  transpose_split_kernel<<<dim3(32, 32), blk, 0, stream>>>(W_syn + (size_t)Dn * Dn, Dn, WbTh, WbTl, Dn);
  transpose_split_kernel<<<dim3(8, 32), blk, 0, stream>>>(W_in, Dn, WinTh, WinTl, DIN);
  transpose_split_kernel<<<dim3(8, 8), blk, 0, stream>>>(W_out, DOUT, WoTh, WoTl, Pn);
  transpose_split_kernel<<<dim3(8, 8), blk, 0, stream>>>(W_act, DOUT, WaTh, WaTl, Pn);
  split_kernel<<<dim3(Bsz * DIN / 1024), blk, 0, stream>>>(x, xh, xl, Bsz * DIN / 4);
  // q = z0 @ W_syn_top via split-K partials + reduce
  matvec_part_kernel<<<dim3(Dn / 64, 8), blk, 0, stream>>>(z0, W_syn, qpart, Dn, Dn);
  reduce_q_kernel<<<dim3(Dn / 256), blk, 0, stream>>>(qpart, q, Dn, 8);
  // feats = x @ W_in + b_in (split output; bias folded in)
  mfma_gemm<0><<<dim3(256), blk512, 0, stream>>>(xh, xl, WinTh, WinTl, b_in, nullptr, fh, fl,
                                                 Bsz, Dn, DIN, 8, 32);
  // base = feats @ W_syn_bot + b_syn
  mfma_gemm<1><<<dim3(256), blk512, 0, stream>>>(fh, fl, WbTh, WbTl, b_syn, base, nullptr, nullptr,
                                                 Bsz, Dn, Dn, 8, 32);
  // tick 0
  tick0_kernel<<<dim3(512), blk, 0, stream>>>(base, q, hist, w1, b1, w2, b2,
                                              zbh[0], zbl[0], zT);
  // ticks 1..7
  for (int tau = 1; tau < TT; ++tau) {
    const unsigned short* zih = zbh[(tau + 1) & 1];
    const unsigned short* zil = zbl[(tau + 1) & 1];
    unsigned short* zoh = zbh[tau & 1];
    unsigned short* zol = zbl[tau & 1];
    float* ho = hist + (size_t)tau * BD;
    unsigned short* zTo = zT + (size_t)tau * BD;
    switch (tau) {
      case 1: tick_mfma<1><<<dim3(256), blk512, 0, stream>>>(zih, zil, WtTh, WtTl, base, hist, ho, w1, b1, w2, b2, zoh, zol, zTo); break;
      case 2: tick_mfma<2><<<dim3(256), blk512, 0, stream>>>(zih, zil, WtTh, WtTl, base, hist, ho, w1, b1, w2, b2, zoh, zol, zTo); break;
      case 3: tick_mfma<3><<<dim3(256), blk512, 0, stream>>>(zih, zil, WtTh, WtTl, base, hist, ho, w1, b1, w2, b2, zoh, zol, zTo); break;
      case 4: tick_mfma<4><<<dim3(256), blk512, 0, stream>>>(zih, zil, WtTh, WtTl, base, hist, ho, w1, b1, w2, b2, zoh, zol, zTo); break;
      case 5: tick_mfma<5><<<dim3(256), blk512, 0, stream>>>(zih, zil, WtTh, WtTl, base, hist, ho, w1, b1, w2, b2, zoh, zol, zTo); break;
      case 6: tick_mfma<6><<<dim3(256), blk512, 0, stream>>>(zih, zil, WtTh, WtTl, base, hist, ho, w1, b1, w2, b2, zoh, zol, zTo); break;
      case 7: tick_mfma<7><<<dim3(256), blk512, 0, stream>>>(zih, zil, WtTh, WtTl, base, hist, ho, w1, b1, w2, b2, zoh, zol, zTo); break;
    }
  }
  // batched sync for both sets
  sync_kernel<<<dim3(Pn / 8, 2), dim3(512), 0, stream>>>(zT, pairs_out, pairs_act,
                                                         decay_out, decay_act,
                                                         Sh0, Sl0, Sh1, Sl1);
  // output GEMMs over all (t, b) rows
  mfma_gemm<2><<<dim3(512), blk512, 0, stream>>>(Sh0, Sl0, WoTh, WoTl, b_out, outy, nullptr, nullptr,
                                                 TT * Bsz, DOUT, Pn, 64, 8);
  mfma_gemm<2><<<dim3(512), blk512, 0, stream>>>(Sh1, Sl1, WaTh, WaTl, b_act, outq, nullptr, nullptr,
                                                 TT * Bsz, DOUT, Pn, 64, 8);
}

// Round 10
// 314.494 us; speedup vs baseline: 1.4902x; 1.0103x over previous
//
#include <hip/hip_runtime.h>
#include <math.h>

#define Bsz 512
#define TT 8
#define Dn 2048
#define DIN 512
#define Hh 4
#define Pn 512
#define DOUT 512
#define BD (Bsz*Dn)

typedef __attribute__((ext_vector_type(8))) short s16x8;
typedef __attribute__((ext_vector_type(4))) float f32x4;
typedef __attribute__((ext_vector_type(4))) unsigned short u16x4;

__device__ __forceinline__ unsigned short f2bf(float f) {
  unsigned int u = __float_as_uint(f);
  unsigned int r = (u + 0x7fffu + ((u >> 16) & 1u)) >> 16;
  return (unsigned short)r;
}
__device__ __forceinline__ float bf2f(unsigned short h) {
  return __uint_as_float(((unsigned int)h) << 16);
}
__device__ __forceinline__ void split2(float x, unsigned short& h, unsigned short& l) {
  h = f2bf(x);
  float r = x - bf2f(h);
  l = f2bf(r);
}

// async global->LDS, 16B per lane, LDS dest = wave-uniform base + lane*16
#define GLOAD16(g, l) __builtin_amdgcn_global_load_lds( \
    (const __attribute__((address_space(1))) unsigned int*)(g), \
    (__attribute__((address_space(3))) unsigned int*)(l), 16, 0, 0)

// ---------------- MFMA GEMM core (r10: dual K-parity, BK=64, ring-2) --------
// A (M,K) h/l bf16 row-major; B as BT h/l (N,K) row-major.
// 64x64 block tile, 512 threads = 2 groups (K-parity) x 4 waves (32x32
// quadrants). Each group-step covers 64 K (group g owns slices (2i+g)*64);
// ring-2 LDS per group; stage(i+1) issued right after the barrier so it has a
// full 24-MFMA compute phase in flight. r9 used BK=32 (32 barriers/tick) and
// the per-phase barrier+waitcnt fixed cost dominated (~190us over 7 ticks);
// halving phases and doubling the MFMA cluster amortizes it (T3 mechanism).
// setprio(1) wraps the MFMA clusters (T5: the two groups sit at different
// phases, so priority arbitration has role diversity to exploit).
// LDS shorts: A bufs (g*2+ring)*8192 in [0,32768); B same at +32768. 128KB.
__device__ __forceinline__ void gemm_core(
    const unsigned short* __restrict__ Ah, const unsigned short* __restrict__ Al,
    const unsigned short* __restrict__ BTh, const unsigned short* __restrict__ BTl,
    int K, long arow0, long brow0,
    unsigned short* LDS, f32x4 acc[2][2], int g, int qw)
{
  const int tid = threadIdx.x;
  const int lane = tid & 63;
  // staging: wave covers A rows [qw*16,+16) and B rows [qw*16,+16), 4 gloads
  // each (one per 4-row slab, 16 slots of 8 shorts per row, row stride 128).
  // Lane l: row += l>>4, slot sc = l&15: part = sc>=8, kg_stored = (sc&7)^(row&7)
  // (XOR swizzle folded into the global source address; LDS dest stays linear).
  const int lh = lane >> 4, sc = lane & 15;
  const unsigned short* gsrc[8];
  int ldst[8];
#pragma unroll
  for (int t = 0; t < 4; ++t) {
    int rb = qw * 16 + t * 4;
    int row = rb + lh;
    int ko = ((sc & 7) ^ (row & 7)) << 3;
    gsrc[t]     = (sc >= 8 ? Al : Ah) + (size_t)(arow0 + row) * K + ko;
    ldst[t]     = rb * 128;
    gsrc[4 + t] = (sc >= 8 ? BTl : BTh) + (size_t)(brow0 + row) * K + ko;
    ldst[4 + t] = 32768 + rb * 128;
  }

  const int nI = K >> 7;   // group-steps of 64 K each; >= 4 at all call sites

#define STAGE(ring, i_)                                              \
  {                                                                  \
    const size_t kb = ((size_t)(2 * (i_) + g)) << 6;                 \
    unsigned short* base = LDS + (g * 2 + (ring)) * 8192;            \
    GLOAD16(gsrc[0] + kb, base + ldst[0]);                           \
    GLOAD16(gsrc[1] + kb, base + ldst[1]);                           \
    GLOAD16(gsrc[2] + kb, base + ldst[2]);                           \
    GLOAD16(gsrc[3] + kb, base + ldst[3]);                           \
    GLOAD16(gsrc[4] + kb, base + ldst[4]);                           \
    GLOAD16(gsrc[5] + kb, base + ldst[5]);                           \
    GLOAD16(gsrc[6] + kb, base + ldst[6]);                           \
    GLOAD16(gsrc[7] + kb, base + ldst[7]);                           \
  }

  // fragment LDS offsets (shorts); quadrant (qw&1)=M half, (qw>>1)=N half.
  // u in 0..1 selects the 32-K window; kg = u*4 + (lane>>4).
  const int wm = (qw & 1) * 32, wn = (qw >> 1) * 32;
  const int lm = lane & 15, kg4 = lane >> 4;
  int aoh[2][2], boh[2][2];
#pragma unroll
  for (int u = 0; u < 2; ++u) {
    int kg = u * 4 + kg4;
#pragma unroll
    for (int mt = 0; mt < 2; ++mt) {
      int ar = wm + mt * 16 + lm;
      aoh[u][mt] = ar * 128 + ((kg ^ (ar & 7)) << 3);
    }
#pragma unroll
    for (int nt = 0; nt < 2; ++nt) {
      int br = wn + nt * 16 + lm;
      boh[u][nt] = br * 128 + ((kg ^ (br & 7)) << 3);
    }
  }

  STAGE(0, 0);
  for (int i = 0; i < nI; ++i) {
    // stage(i) complete (flight = previous compute phase); publish via barrier
    asm volatile("s_waitcnt vmcnt(0)" ::: "memory");
    __builtin_amdgcn_s_barrier();
    if (i + 1 < nI) STAGE((i + 1) & 1, i + 1);
    const unsigned short* ab = LDS + (g * 2 + (i & 1)) * 8192;
    const unsigned short* bb = ab + 32768;
#pragma unroll
    for (int u = 0; u < 2; ++u) {
      s16x8 fah[2], fal[2], fbh[2], fbl[2];
#pragma unroll
      for (int mt = 0; mt < 2; ++mt) {
        fah[mt] = *(const s16x8*)(ab + aoh[u][mt]);
        fal[mt] = *(const s16x8*)(ab + aoh[u][mt] + 64);
      }
#pragma unroll
      for (int nt = 0; nt < 2; ++nt) {
        fbh[nt] = *(const s16x8*)(bb + boh[u][nt]);
        fbl[nt] = *(const s16x8*)(bb + boh[u][nt] + 64);
      }
      __builtin_amdgcn_s_setprio(1);
#pragma unroll
      for (int mt = 0; mt < 2; ++mt)
#pragma unroll
        for (int nt = 0; nt < 2; ++nt) {
          acc[mt][nt] = __builtin_amdgcn_mfma_f32_16x16x32_bf16(fah[mt], fbh[nt], acc[mt][nt], 0, 0, 0);
          acc[mt][nt] = __builtin_amdgcn_mfma_f32_16x16x32_bf16(fah[mt], fbl[nt], acc[mt][nt], 0, 0, 0);
          acc[mt][nt] = __builtin_amdgcn_mfma_f32_16x16x32_bf16(fal[mt], fbh[nt], acc[mt][nt], 0, 0, 0);
        }
      __builtin_amdgcn_s_setprio(0);
    }
  }
#undef STAGE

  // cross-group reduction: group1 -> LDS (pad 17 floats), group0 adds.
  __builtin_amdgcn_s_barrier();
  float* fred = (float*)LDS;
  const int ridx = (qw * 64 + lane) * 17;
  if (g == 1) {
#pragma unroll
    for (int mt = 0; mt < 2; ++mt)
#pragma unroll
      for (int nt = 0; nt < 2; ++nt)
#pragma unroll
        for (int r = 0; r < 4; ++r)
          fred[ridx + (mt * 2 + nt) * 4 + r] = acc[mt][nt][r];
  }
  __builtin_amdgcn_s_barrier();
  if (g == 0) {
#pragma unroll
    for (int mt = 0; mt < 2; ++mt)
#pragma unroll
      for (int nt = 0; nt < 2; ++nt)
#pragma unroll
        for (int r = 0; r < 4; ++r)
          acc[mt][nt][r] += fred[ridx + (mt * 2 + nt) * 4 + r];
  }
}

// MODE 0: split bf16 out + bias. MODE 1: fp32 out + bias. MODE 2: out scatter + bias.
template<int MODE>
__global__ __launch_bounds__(512, 1)
void mfma_gemm(const unsigned short* __restrict__ Ah, const unsigned short* __restrict__ Al,
               const unsigned short* __restrict__ BTh, const unsigned short* __restrict__ BTl,
               const float* __restrict__ bias, float* __restrict__ Cf,
               unsigned short* __restrict__ Ch, unsigned short* __restrict__ Cl,
               int M, int N, int K, int gm, int gn)
{
  __shared__ unsigned short LDS[65536];
  int bid = blockIdx.x;
  int xcd = bid & 7, w = bid >> 3;
  int bmi = w % gm, bni = xcd * (gn >> 3) + w / gm;
  long bm = (long)bmi * 64, bn = (long)bni * 64;
  const int tid = threadIdx.x, lane = tid & 63, wave = tid >> 6;
  const int g = wave >> 2, qw = wave & 3;
  f32x4 acc[2][2];
#pragma unroll
  for (int a = 0; a < 2; ++a)
#pragma unroll
    for (int b = 0; b < 2; ++b) acc[a][b] = (f32x4)0.f;
  gemm_core(Ah, Al, BTh, BTl, K, bm, bn, LDS, acc, g, qw);
  if (g == 1) return;

  const int wm = (qw & 1) * 32, wn = (qw >> 1) * 32;
#pragma unroll
  for (int nt = 0; nt < 2; ++nt) {
    int n = (int)bn + wn + nt * 16 + (lane & 15);
    float bv = bias[n];
#pragma unroll
    for (int mt = 0; mt < 2; ++mt) {
      long r0 = bm + wm + mt * 16 + (lane >> 4) * 4;
#pragma unroll
      for (int r = 0; r < 4; ++r) {
        float v = acc[mt][nt][r] + bv;
        long R = r0 + r;
        if (MODE == 0) {
          unsigned short h_, l_; split2(v, h_, l_);
          Ch[R * N + n] = h_; Cl[R * N + n] = l_;
        } else if (MODE == 1) {
          Cf[R * N + n] = v;
        } else {
          long t = R >> 9, b = R & 511;
          Cf[(b * TT + t) * N + n] = v;
        }
      }
    }
  }
}

// ---------------- tick kernel (tau >= 1): GEMM + base + NLM epilogue ----------
template<int TAU>
__global__ __launch_bounds__(512, 1)
void tick_mfma(const unsigned short* __restrict__ zh, const unsigned short* __restrict__ zl,
               const unsigned short* __restrict__ WTh, const unsigned short* __restrict__ WTl,
               const float* __restrict__ basep, const float* __restrict__ hist,
               float* __restrict__ histout,
               const float* __restrict__ w1, const float* __restrict__ b1,
               const float* __restrict__ w2, const float* __restrict__ b2,
               unsigned short* __restrict__ zho, unsigned short* __restrict__ zlo,
               unsigned short* __restrict__ zT)
{
  __shared__ unsigned short LDS[65536];
  int bid = blockIdx.x;
  int xcd = bid & 7, w = bid >> 3;
  int bmi = w % 8, bni = xcd * 4 + w / 8;
  long bm = (long)bmi * 64, bn = (long)bni * 64;
  const int tid = threadIdx.x, lane = tid & 63, wave = tid >> 6;
  const int g = wave >> 2, qw = wave & 3;
  f32x4 acc[2][2];
#pragma unroll
  for (int a = 0; a < 2; ++a)
#pragma unroll
    for (int b = 0; b < 2; ++b) acc[a][b] = (f32x4)0.f;
  gemm_core(zh, zl, WTh, WTl, Dn, bm, bn, LDS, acc, g, qw);
  if (g == 1) return;

  const int wm = (qw & 1) * 32, wn = (qw >> 1) * 32;
#pragma unroll
  for (int nt = 0; nt < 2; ++nt) {
    const int d = (int)bn + wn + nt * 16 + (lane & 15);
    float w2v[Hh], b1v[Hh];
#pragma unroll
    for (int hh = 0; hh < Hh; ++hh) {
      w2v[hh] = w2[hh * Dn + d];
      b1v[hh] = b1[hh * Dn + d];
    }
    const float b2v = b2[d];
#pragma unroll
    for (int mt = 0; mt < 2; ++mt) {
      const int b0 = (int)bm + wm + mt * 16 + (lane >> 4) * 4;
      float pre[4], hacc[4][Hh];
#pragma unroll
      for (int r = 0; r < 4; ++r) {
        pre[r] = acc[mt][nt][r] + basep[(size_t)(b0 + r) * Dn + d];
#pragma unroll
        for (int hh = 0; hh < Hh; ++hh) hacc[r][hh] = b1v[hh];
      }
#pragma unroll
      for (int s = 0; s < TAU; ++s) {
        float wv[Hh];
#pragma unroll
        for (int hh = 0; hh < Hh; ++hh) wv[hh] = w1[((15 - TAU + s) * Hh + hh) * Dn + d];
#pragma unroll
        for (int r = 0; r < 4; ++r) {
          float psv = hist[(size_t)s * BD + (size_t)(b0 + r) * Dn + d];
#pragma unroll
          for (int hh = 0; hh < Hh; ++hh) hacc[r][hh] = fmaf(psv, wv[hh], hacc[r][hh]);
        }
      }
      {
        float wv[Hh];
#pragma unroll
        for (int hh = 0; hh < Hh; ++hh) wv[hh] = w1[(15 * Hh + hh) * Dn + d];
#pragma unroll
        for (int r = 0; r < 4; ++r)
#pragma unroll
          for (int hh = 0; hh < Hh; ++hh) hacc[r][hh] = fmaf(pre[r], wv[hh], hacc[r][hh]);
      }
      u16x4 pack;
#pragma unroll
      for (int r = 0; r < 4; ++r) {
        histout[(size_t)(b0 + r) * Dn + d] = pre[r];
        float z = b2v;
#pragma unroll
        for (int hh = 0; hh < Hh; ++hh) z = fmaf(fmaxf(hacc[r][hh], 0.f), w2v[hh], z);
        unsigned short h_, l_; split2(z, h_, l_);
        zho[(size_t)(b0 + r) * Dn + d] = h_;
        zlo[(size_t)(b0 + r) * Dn + d] = l_;
        pack[r] = f2bf(z);
      }
      *(u16x4*)&zT[(size_t)d * Bsz + b0] = pack;
    }
  }
}

// ---------------- tick 0: pre = base + q, NLM single term --------------------
__global__ __launch_bounds__(256)
void tick0_kernel(const float* __restrict__ basep, const float* __restrict__ q,
                  float* __restrict__ histout,
                  const float* __restrict__ w1, const float* __restrict__ b1,
                  const float* __restrict__ w2, const float* __restrict__ b2,
                  unsigned short* __restrict__ zho, unsigned short* __restrict__ zlo,
                  unsigned short* __restrict__ zT)
{
  int g = blockIdx.x * 256 + threadIdx.x;
  int b = g >> 8;
  int d0 = (g & 255) * 8;
#pragma unroll
  for (int k = 0; k < 8; ++k) {
    int d = d0 + k;
    float pre = basep[(size_t)b * Dn + d] + q[d];
    histout[(size_t)b * Dn + d] = pre;
    float z = b2[d];
#pragma unroll
    for (int hh = 0; hh < Hh; ++hh) {
      float h = fmaf(pre, w1[(15 * Hh + hh) * Dn + d], b1[hh * Dn + d]);
      z = fmaf(fmaxf(h, 0.f), w2[hh * Dn + d], z);
    }
    unsigned short h_, l_; split2(z, h_, l_);
    zho[(size_t)b * Dn + d] = h_;
    zlo[(size_t)b * Dn + d] = l_;
    zT[(size_t)d * Bsz + b] = f2bf(z);
  }
}

// ---------------- batched sync: S for all ticks, both sets -------------------
__global__ __launch_bounds__(512)
void sync_kernel(const unsigned short* __restrict__ zT,
                 const int* __restrict__ pairs0, const int* __restrict__ pairs1,
                 const float* __restrict__ decay0, const float* __restrict__ decay1,
                 unsigned short* __restrict__ Sh0, unsigned short* __restrict__ Sl0,
                 unsigned short* __restrict__ Sh1, unsigned short* __restrict__ Sl1)
{
  __shared__ float Ls[8][8][65];
  const int set = blockIdx.y;
  const int* pairs = set ? pairs1 : pairs0;
  const float* decay = set ? decay1 : decay0;
  unsigned short* Sh = set ? Sh1 : Sh0;
  unsigned short* Sl = set ? Sl1 : Sl0;
  const int tid = threadIdx.x;
  const int lb = tid & 63, pl = tid >> 6;
  const int p = blockIdx.x * 8 + pl;
  const int i = pairs[2 * p], j = pairs[2 * p + 1];
  const float r = expf(-fabsf(decay[p]));
  const int pb = tid & 7, bb2 = tid >> 3;
  for (int bb = 0; bb < 8; ++bb) {
    int b = bb * 64 + lb;
    float S = 0.f, St[8];
#pragma unroll
    for (int t = 0; t < 8; ++t) {
      float zi = bf2f(zT[(size_t)t * BD + (size_t)i * Bsz + b]);
      float zj = bf2f(zT[(size_t)t * BD + (size_t)j * Bsz + b]);
      S = fmaf(S, r, zi * zj);
      St[t] = S;
    }
#pragma unroll
    for (int t = 0; t < 8; ++t) Ls[pl][t][lb] = St[t];
    __syncthreads();
#pragma unroll
    for (int t = 0; t < 8; ++t) {
      float v = Ls[pb][t][bb2];
      unsigned short h_, l_; split2(v, h_, l_);
      size_t off = ((size_t)t * Bsz + bb * 64 + bb2) * Pn + blockIdx.x * 8 + pb;
      Sh[off] = h_; Sl[off] = l_;
    }
    __syncthreads();
  }
}

// ---------------- weight transpose + bf16x2 split: (K,N) -> h/l (N,K) --------
__global__ __launch_bounds__(256)
void transpose_split_kernel(const float* __restrict__ in, int ldin,
                            unsigned short* __restrict__ Th, unsigned short* __restrict__ Tl,
                            int K)
{
  __shared__ float T[64][65];
  int k0 = blockIdx.x * 64, n0 = blockIdx.y * 64;
  int tid = threadIdx.x;
  int r = tid >> 2, c0 = (tid & 3) * 16;
#pragma unroll
  for (int cc = 0; cc < 16; cc += 4) {
    float4 v = *(const float4*)(in + (size_t)(k0 + r) * ldin + n0 + c0 + cc);
    T[c0 + cc + 0][r] = v.x; T[c0 + cc + 1][r] = v.y;
    T[c0 + cc + 2][r] = v.z; T[c0 + cc + 3][r] = v.w;
  }
  __syncthreads();
  int n = tid >> 2, kc = (tid & 3) * 16;
#pragma unroll
  for (int kk = 0; kk < 16; ++kk) {
    float v = T[n][kc + kk];
    unsigned short h_, l_; split2(v, h_, l_);
    Th[(size_t)(n0 + n) * K + k0 + kc + kk] = h_;
    Tl[(size_t)(n0 + n) * K + k0 + kc + kk] = l_;
  }
}

// ---------------- elementwise split (x) --------------------------------------
__global__ __launch_bounds__(256)
void split_kernel(const float* __restrict__ x, unsigned short* __restrict__ xh,
                  unsigned short* __restrict__ xl, int n4)
{
  int i = blockIdx.x * 256 + threadIdx.x;
  if (i >= n4) return;
  float4 v = *(const float4*)(x + (size_t)i * 4);
  u16x4 h, l;
  unsigned short th, tl;
  split2(v.x, th, tl); h[0] = th; l[0] = tl;
  split2(v.y, th, tl); h[1] = th; l[1] = tl;
  split2(v.z, th, tl); h[2] = th; l[2] = tl;
  split2(v.w, th, tl); h[3] = th; l[3] = tl;
  *(u16x4*)(xh + (size_t)i * 4) = h;
  *(u16x4*)(xl + (size_t)i * 4) = l;
}

// ---------------- split-K matvec partials: part[kc][col] ---------------------
__global__ __launch_bounds__(256)
void matvec_part_kernel(const float* __restrict__ vec, const float* __restrict__ W,
                        float* __restrict__ part, int K, int N)
{
  __shared__ float red[4][64];
  const int tid = threadIdx.x;
  const int c = tid & 63, strip = tid >> 6;
  const int col = blockIdx.x * 64 + c;
  const int kpc = K / (gridDim.y * 4);
  const int k0 = (blockIdx.y * 4 + strip) * kpc;
  float acc = 0.f;
#pragma unroll 8
  for (int k = k0; k < k0 + kpc; ++k)
    acc = fmaf(vec[k], W[(size_t)k * N + col], acc);
  red[strip][c] = acc;
  __syncthreads();
  if (strip == 0)
    part[(size_t)blockIdx.y * N + col] = red[0][c] + red[1][c] + red[2][c] + red[3][c];
}

__global__ __launch_bounds__(256)
void reduce_q_kernel(const float* __restrict__ part, float* __restrict__ q, int N, int C)
{
  int d = blockIdx.x * 256 + threadIdx.x;
  if (d >= N) return;
  float s = 0.f;
  for (int c = 0; c < C; ++c) s += part[(size_t)c * N + d];
  q[d] = s;
}

extern "C" void kernel_launch(void* const* d_in, const int* in_sizes, int n_in,
                              void* d_out, int out_size, void* d_ws, size_t ws_size,
                              hipStream_t stream) {
  const float* x      = (const float*)d_in[0];
  const float* W_in   = (const float*)d_in[1];
  const float* b_in   = (const float*)d_in[2];
  const float* z0     = (const float*)d_in[3];
  const float* W_syn  = (const float*)d_in[4];
  const float* b_syn  = (const float*)d_in[5];
  const float* w1     = (const float*)d_in[6];
  const float* b1     = (const float*)d_in[7];
  const float* w2     = (const float*)d_in[8];
  const float* b2     = (const float*)d_in[9];
  const float* decay_out = (const float*)d_in[10];
  const float* decay_act = (const float*)d_in[11];
  const float* W_out  = (const float*)d_in[12];
  const float* b_out  = (const float*)d_in[13];
  const float* W_act  = (const float*)d_in[14];
  const float* b_act  = (const float*)d_in[15];
  const int* pairs_out = (const int*)d_in[16];
  const int* pairs_act = (const int*)d_in[17];

  char* W = (char*)d_ws;
  auto alloc = [&](size_t bytes) { char* p = W; W += (bytes + 255) & ~255ull; return p; };
  unsigned short* WtTh = (unsigned short*)alloc((size_t)Dn * Dn * 2);
  unsigned short* WtTl = (unsigned short*)alloc((size_t)Dn * Dn * 2);
  unsigned short* WbTh = (unsigned short*)alloc((size_t)Dn * Dn * 2);
  unsigned short* WbTl = (unsigned short*)alloc((size_t)Dn * Dn * 2);
  unsigned short* WinTh = (unsigned short*)alloc((size_t)Dn * DIN * 2);
  unsigned short* WinTl = (unsigned short*)alloc((size_t)Dn * DIN * 2);
  unsigned short* WoTh = (unsigned short*)alloc((size_t)DOUT * Pn * 2);
  unsigned short* WoTl = (unsigned short*)alloc((size_t)DOUT * Pn * 2);
  unsigned short* WaTh = (unsigned short*)alloc((size_t)DOUT * Pn * 2);
  unsigned short* WaTl = (unsigned short*)alloc((size_t)DOUT * Pn * 2);
  unsigned short* xh = (unsigned short*)alloc((size_t)Bsz * DIN * 2);
  unsigned short* xl = (unsigned short*)alloc((size_t)Bsz * DIN * 2);
  unsigned short* fh = (unsigned short*)alloc((size_t)BD * 2);
  unsigned short* fl = (unsigned short*)alloc((size_t)BD * 2);
  float* q     = (float*)alloc(Dn * 4);
  float* qpart = (float*)alloc(8 * Dn * 4);
  float* base  = (float*)alloc((size_t)BD * 4);
  float* hist  = (float*)alloc((size_t)TT * BD * 4);
  unsigned short* zbh[2], *zbl[2];
  zbh[0] = (unsigned short*)alloc((size_t)BD * 2);
  zbl[0] = (unsigned short*)alloc((size_t)BD * 2);
  zbh[1] = (unsigned short*)alloc((size_t)BD * 2);
  zbl[1] = (unsigned short*)alloc((size_t)BD * 2);
  unsigned short* zT = (unsigned short*)alloc((size_t)TT * BD * 2);
  // S buffers alias the (dead-after-base-GEMM) WbT region: 4MB each
  unsigned short* Sh0 = WbTh;
  unsigned short* Sl0 = WbTh + (size_t)TT * Bsz * Pn;
  unsigned short* Sh1 = WbTl;
  unsigned short* Sl1 = WbTl + (size_t)TT * Bsz * Pn;

  float* outy = (float*)d_out;
  float* outq = outy + (size_t)Bsz * TT * DOUT;

  dim3 blk(256);
  dim3 blk512(512);
  // weight prep
  transpose_split_kernel<<<dim3(32, 32), blk, 0, stream>>>(W_syn, Dn, WtTh, WtTl, Dn);
  transpose_split_kernel<<<dim3(32, 32), blk, 0, stream>>>(W_syn + (size_t)Dn * Dn, Dn, WbTh, WbTl, Dn);
  transpose_split_kernel<<<dim3(8, 32), blk, 0, stream>>>(W_in, Dn, WinTh, WinTl, DIN);
  transpose_split_kernel<<<dim3(8, 8), blk, 0, stream>>>(W_out, DOUT, WoTh, WoTl, Pn);
  transpose_split_kernel<<<dim3(8, 8), blk, 0, stream>>>(W_act, DOUT, WaTh, WaTl, Pn);
  split_kernel<<<dim3(Bsz * DIN / 1024), blk, 0, stream>>>(x, xh, xl, Bsz * DIN / 4);
  // q = z0 @ W_syn_top via split-K partials + reduce
  matvec_part_kernel<<<dim3(Dn / 64, 8), blk, 0, stream>>>(z0, W_syn, qpart, Dn, Dn);
  reduce_q_kernel<<<dim3(Dn / 256), blk, 0, stream>>>(qpart, q, Dn, 8);
  // feats = x @ W_in + b_in (split output; bias folded in)
  mfma_gemm<0><<<dim3(256), blk512, 0, stream>>>(xh, xl, WinTh, WinTl, b_in, nullptr, fh, fl,
                                                 Bsz, Dn, DIN, 8, 32);
  // base = feats @ W_syn_bot + b_syn
  mfma_gemm<1><<<dim3(256), blk512, 0, stream>>>(fh, fl, WbTh, WbTl, b_syn, base, nullptr, nullptr,
                                                 Bsz, Dn, Dn, 8, 32);
  // tick 0
  tick0_kernel<<<dim3(512), blk, 0, stream>>>(base, q, hist, w1, b1, w2, b2,
                                              zbh[0], zbl[0], zT);
  // ticks 1..7
  for (int tau = 1; tau < TT; ++tau) {
    const unsigned short* zih = zbh[(tau + 1) & 1];
    const unsigned short* zil = zbl[(tau + 1) & 1];
    unsigned short* zoh = zbh[tau & 1];
    unsigned short* zol = zbl[tau & 1];
    float* ho = hist + (size_t)tau * BD;
    unsigned short* zTo = zT + (size_t)tau * BD;
    switch (tau) {
      case 1: tick_mfma<1><<<dim3(256), blk512, 0, stream>>>(zih, zil, WtTh, WtTl, base, hist, ho, w1, b1, w2, b2, zoh, zol, zTo); break;
      case 2: tick_mfma<2><<<dim3(256), blk512, 0, stream>>>(zih, zil, WtTh, WtTl, base, hist, ho, w1, b1, w2, b2, zoh, zol, zTo); break;
      case 3: tick_mfma<3><<<dim3(256), blk512, 0, stream>>>(zih, zil, WtTh, WtTl, base, hist, ho, w1, b1, w2, b2, zoh, zol, zTo); break;
      case 4: tick_mfma<4><<<dim3(256), blk512, 0, stream>>>(zih, zil, WtTh, WtTl, base, hist, ho, w1, b1, w2, b2, zoh, zol, zTo); break;
      case 5: tick_mfma<5><<<dim3(256), blk512, 0, stream>>>(zih, zil, WtTh, WtTl, base, hist, ho, w1, b1, w2, b2, zoh, zol, zTo); break;
      case 6: tick_mfma<6><<<dim3(256), blk512, 0, stream>>>(zih, zil, WtTh, WtTl, base, hist, ho, w1, b1, w2, b2, zoh, zol, zTo); break;
      case 7: tick_mfma<7><<<dim3(256), blk512, 0, stream>>>(zih, zil, WtTh, WtTl, base, hist, ho, w1, b1, w2, b2, zoh, zol, zTo); break;
    }
  }
  // batched sync for both sets
  sync_kernel<<<dim3(Pn / 8, 2), dim3(512), 0, stream>>>(zT, pairs_out, pairs_act,
                                                         decay_out, decay_act,
                                                         Sh0, Sl0, Sh1, Sl1);
  // output GEMMs over all (t, b) rows
  mfma_gemm<2><<<dim3(512), blk512, 0, stream>>>(Sh0, Sl0, WoTh, WoTl, b_out, outy, nullptr, nullptr,
                                                 TT * Bsz, DOUT, Pn, 64, 8);
  mfma_gemm<2><<<dim3(512), blk512, 0, stream>>>(Sh1, Sl1, WaTh, WaTl, b_act, outq, nullptr, nullptr,
                                                 TT * Bsz, DOUT, Pn, 64, 8);
}